// Round 1
// baseline (181.104 us; speedup 1.0000x reference)
//
#include <hip/hip_runtime.h>

typedef unsigned short u16;
typedef unsigned int u32;
typedef __attribute__((ext_vector_type(8))) short short8;
typedef __attribute__((ext_vector_type(4))) float floatx4;
typedef __attribute__((ext_vector_type(4))) u32 u32x4;

#define NUMS 2048
#define DIM 128
#define ROWS_TOT 16384
#define HALF_ROWS 8192
#define KTOP 129
#define MTILE 16
#define SCALE 0.08838834764831845f

__device__ __forceinline__ u16 f2bf(float f) {
  u32 u = __builtin_bit_cast(u32, f);
  u += 0x7FFFu + ((u >> 16) & 1u);
  return (u16)(u >> 16);
}
__device__ __forceinline__ float bf2f(u32 b) {
  return __builtin_bit_cast(float, b << 16);
}

// weight fp32 [2048][128] -> wb bf16 [2048][128] (row-major, for GEMM1)
//                         -> wt bf16 [128][2048] (transposed, for GEMM2) with a
// within-32 permutation of the k index:  storage col = (k & ~31) | s,
//   s = 8*((k>>2)&3) + 4*((k>>4)&1) + (k&3)
// Chosen so that fused_k's GEMM2 A-fragment (contiguous short8 at chunk*32 +
// quad*8) pairs element-for-element with the B-fragment that is *exactly*
// GEMM1's packed accumulator registers (no shuffle, no LDS staging).
__global__ void cvt_w_k(const float* __restrict__ w, u16* __restrict__ wb,
                        u16* __restrict__ wt) {
  __shared__ u16 tile[32][33];
  const int tx = threadIdx.x, ty = threadIdx.y;
  const int x = blockIdx.x * 32 + tx;  // col in W (0..127)
  const int y0 = blockIdx.y * 32;      // row block in W
#pragma unroll
  for (int j = 0; j < 32; j += 8) {
    const u16 v = f2bf(w[(size_t)(y0 + ty + j) * DIM + x]);
    wb[(size_t)(y0 + ty + j) * DIM + x] = v;
    tile[ty + j][tx] = v;
  }
  __syncthreads();
  const int k = y0 + tx;  // actual k (row of W = att col)
  const int s = ((k >> 2) & 3) * 8 + ((k >> 4) & 1) * 4 + (k & 3);
  const int x2p = (k & ~31) | s;        // permuted storage col
  const int y2 = blockIdx.x * 32 + ty;  // row in Wt (= col in W)
#pragma unroll
  for (int j = 0; j < 32; j += 8)
    wt[(size_t)(y2 + j) * NUMS + x2p] = tile[tx][ty + j];
}

__global__ __launch_bounds__(512, 6)
void fused_k(const float* __restrict__ dataF, const u16* __restrict__ wb,
             const u16* __restrict__ wt, float* __restrict__ out) {
  // LDS: only small reduction buffers (~10.6 KB) -> 3+ blocks/CU
  __shared__ floatx4 accb4[16 * 32];  // augment accum f32 [16 rows][128 cols], col^row swizzled
  __shared__ u32x4 cntb[16][8];       // per-row, per-wave packed counts (8 u16)
  __shared__ float vbuf[16];          // v* per row
  __shared__ u32 cbuf[16];            // cnt(> v*) per row
  __shared__ u32 basebuf[16];         // probe-window base code per row
  __shared__ float sumbuf[16];        // sum of vals > v* per row
  __shared__ u32 dbuf[16];            // row resolved flag
  __shared__ u32 donecnt;
  float* const accb = (float*)accb4;

  const int tid = threadIdx.x;
  const int r0 = blockIdx.x * MTILE;
  const int lane = tid & 63;
  const int wave = tid >> 6;  // 0..7
  const int m = lane & 15;
  const int quad = lane >> 4;
  const bool firstHalf = (r0 < HALF_ROWS);

  // ---- init phase ----
  if (firstHalf) accb4[tid] = (floatx4){0.f, 0.f, 0.f, 0.f};
  if (tid < 16) {
    sumbuf[tid] = 0.f;
    dbuf[tid] = 0u;
    basebuf[tid] = 0x3F00u;  // bf16 code of 0.5
  }
  if (tid == 16) donecnt = 0u;
  __syncthreads();  // bar0: zero-init visible before any ds_add

  // ---- B-operand fragments: data rows, fp32 -> bf16 inline ----
  short8 dfrag[4];
  {
    const float* ap = dataF + (r0 + m) * DIM + quad * 8;
#pragma unroll
    for (int ks = 0; ks < 4; ks++) {
      const float4 x = *(const float4*)(ap + ks * 32);
      const float4 y = *(const float4*)(ap + ks * 32 + 4);
      short8 v;
      v[0] = (short)f2bf(x.x); v[1] = (short)f2bf(x.y);
      v[2] = (short)f2bf(x.z); v[3] = (short)f2bf(x.w);
      v[4] = (short)f2bf(y.x); v[5] = (short)f2bf(y.y);
      v[6] = (short)f2bf(y.z); v[7] = (short)f2bf(y.w);
      dfrag[ks] = v;
    }
  }

  // ---- GEMM1 (transposed): att kept in registers ----
  // patt[2t+w] at lane (m,quad) = codes of att[col = wave*256+16t+4q+2w+{0,1}][row m]
  u32 patt[32];
#pragma unroll 2
  for (int nt = 0; nt < 16; nt++) {
    const int n0 = wave * 256 + nt * 16;
    const u16* wp = wb + (n0 + m) * DIM + quad * 8;
    floatx4 acc = {0.f, 0.f, 0.f, 0.f};
#pragma unroll
    for (int ks = 0; ks < 4; ks++) {
      const short8 wfrag = *(const short8*)(wp + ks * 32);
      acc = __builtin_amdgcn_mfma_f32_16x16x32_bf16(wfrag, dfrag[ks], acc, 0, 0, 0);
    }
    const float a0 = 1.f / (1.f + __expf(-acc[0] * SCALE));
    const float a1 = 1.f / (1.f + __expf(-acc[1] * SCALE));
    const float a2 = 1.f / (1.f + __expf(-acc[2] * SCALE));
    const float a3 = 1.f / (1.f + __expf(-acc[3] * SCALE));
    patt[2 * nt] = (u32)f2bf(a0) | ((u32)f2bf(a1) << 16);
    patt[2 * nt + 1] = (u32)f2bf(a2) | ((u32)f2bf(a3) << 16);
  }

  // ---- first half: read_query = [data_fp32 | attention @ W] ----
  if (firstHalf) {
    {  // raw fp32 data -> read_query[:, :128]
      const int row = tid >> 5;
      const int c4 = (tid & 31) << 2;
      *(float4*)(out + 16384 + (size_t)(r0 + row) * 256 + c4) =
          *(const float4*)(dataF + (r0 + row) * DIM + c4);
    }
    // GEMM2: this wave's K-partial (its 256 att cols) for ALL 128 out cols.
    // B operand is patt re-interpreted (wt was k-permuted to match in cvt_w_k).
#pragma unroll 1
    for (int nt2 = 0; nt2 < 8; nt2++) {
      const u16* wtp = wt + (nt2 * 16 + m) * NUMS + wave * 256 + quad * 8;
      floatx4 acc = {0.f, 0.f, 0.f, 0.f};
#pragma unroll
      for (int ks2 = 0; ks2 < 8; ks2++) {
        const short8 a = *(const short8*)(wtp + ks2 * 32);
        const u32x4 bb = {patt[4 * ks2], patt[4 * ks2 + 1],
                          patt[4 * ks2 + 2], patt[4 * ks2 + 3]};
        acc = __builtin_amdgcn_mfma_f32_16x16x32_bf16(
            a, __builtin_bit_cast(short8, bb), acc, 0, 0, 0);
      }
      // D: lane (m,q) holds augment[outcol = 16*nt2+4q+i][row m].
      // col^m swizzle: 4-way worst-case bank pattern on ds_add instead of 16-way.
#pragma unroll
      for (int i = 0; i < 4; i++) {
        const int oc = nt2 * 16 + quad * 4 + i;
        atomicAdd(accb + m * 128 + (oc ^ m), acc[i]);
      }
    }
  }

  // ---- top-129 per row: SWAR counts at 8 consecutive bf16 codes ----
  const u32 M8 = 0x80008000u;
  auto count_pub = [&](u32 base) {
    u32 pk[4];
#pragma unroll
    for (int j = 0; j < 4; j++) {
      // (code | 0x8000) - t  ==  code + (0x8000 - t): no cross-half carry
      const u32 uA = M8 - (base + 2u * j) * 0x10001u;
      const u32 uB = uA - 0x10001u;
      u32 cA = 0, cB = 0;
#pragma unroll
      for (int i = 0; i < 32; i++) {
        cA += __popc((patt[i] + uA) & M8);
        cB += __popc((patt[i] + uB) & M8);
      }
      pk[j] = cA | (cB << 16);
    }
#pragma unroll
    for (int j = 0; j < 4; j++) {  // sum the 4 quads of row m
      pk[j] += __shfl_xor(pk[j], 16);
      pk[j] += __shfl_xor(pk[j], 32);
    }
    if (quad == 0)  // wave^(m&7) slot swizzle: conflict-free b128 writes
      cntb[m][wave ^ (m & 7)] = (u32x4){pk[0], pk[1], pk[2], pk[3]};
  };

  auto resolve = [&]() {
    const int rr = wave * 2 + (lane >> 5);  // lanes 0-31: row 2w, 32-63: row 2w+1
    if (dbuf[rr]) return;                   // half-wave uniform; shfl stays in half
    const int L = lane & 31;
    const u32 base = basebuf[rr];
    u32x4 c = cntb[rr][(L & 7) ^ (rr & 7)];
    u32 p0 = c.x, p1 = c.y, p2 = c.z, p3 = c.w;
#pragma unroll
    for (int off = 1; off < 8; off <<= 1) {  // sum over 8 waves
      p0 += __shfl_xor(p0, off);
      p1 += __shfl_xor(p1, off);
      p2 += __shfl_xor(p2, off);
      p3 += __shfl_xor(p3, off);
    }
    const int cw0 = (int)(p0 & 0xFFFFu), cw1 = (int)(p0 >> 16);
    const int cw2 = (int)(p1 & 0xFFFFu), cw3 = (int)(p1 >> 16);
    const int cw4 = (int)(p2 & 0xFFFFu), cw5 = (int)(p2 >> 16);
    const int cw6 = (int)(p3 & 0xFFFFu), cw7 = (int)(p3 >> 16);
    if (cw0 >= KTOP && cw7 < KTOP) {  // 129th value inside window
      const int idx = (cw1 >= KTOP) + (cw2 >= KTOP) + (cw3 >= KTOP) +
                      (cw4 >= KTOP) + (cw5 >= KTOP) + (cw6 >= KTOP) +
                      (cw7 >= KTOP);
      // cgt = cw[idx+1] = largest count < KTOP (counts monotone nonincreasing)
      int cgt = 0;
      cgt = (cw1 < KTOP && cw1 > cgt) ? cw1 : cgt;
      cgt = (cw2 < KTOP && cw2 > cgt) ? cw2 : cgt;
      cgt = (cw3 < KTOP && cw3 > cgt) ? cw3 : cgt;
      cgt = (cw4 < KTOP && cw4 > cgt) ? cw4 : cgt;
      cgt = (cw5 < KTOP && cw5 > cgt) ? cw5 : cgt;
      cgt = (cw6 < KTOP && cw6 > cgt) ? cw6 : cgt;
      cgt = (cw7 < KTOP && cw7 > cgt) ? cw7 : cgt;
      if (L == 0) {
        vbuf[rr] = bf2f(base + (u32)idx);
        cbuf[rr] = (u32)cgt;
        dbuf[rr] = 1u;
        atomicAdd(&donecnt, 1u);
      }
    } else if (L == 0) {  // cold: slide the window (never taken in practice)
      basebuf[rr] = (cw0 < KTOP) ? base - 7u : base + 7u;
    }
  };

  count_pub(0x3F00u);
  __syncthreads();  // bar1: counts published
  resolve();
  __syncthreads();  // bar2: v*/cgt published (or base adjusted)
  while (donecnt < 16u) {  // cold re-probe loop, block-uniform
    count_pub(basebuf[m]);
    __syncthreads();
    resolve();
    __syncthreads();
  }

  // ---- exact top-K sum: sum(vals > v*) + (K - cgt) * v* ----
  {
    const float vst = vbuf[m];
    float s = 0.f;
#pragma unroll
    for (int i = 0; i < 32; i++) {
      const float v0 = bf2f(patt[i] & 0xFFFFu);
      const float v1 = __builtin_bit_cast(float, patt[i] & 0xFFFF0000u);
      if (v0 > vst) s += v0;
      if (v1 > vst) s += v1;
    }
    s += __shfl_xor(s, 16);
    s += __shfl_xor(s, 32);
    if (quad == 0) atomicAdd(&sumbuf[m], s);
  }
  __syncthreads();  // bar3: sums + augment accumulation complete

  if (tid < 16) {
    const float mean = (sumbuf[tid] + (float)(KTOP - (int)cbuf[tid]) * vbuf[tid]) *
                       (1.f / (float)KTOP);
    out[r0 + tid] = 1.f - mean;
  }
  if (firstHalf) {  // augment: unswizzle accbuf -> read_query[:, 128:256]
    const int row = tid >> 5;
    const int c = tid & 31;
    const int r = row & 3;
    floatx4 v = *((floatx4*)(accb + row * 128 + 4 * (c ^ (row >> 2))));
    if (r & 1) { float t = v[0]; v[0] = v[1]; v[1] = t; t = v[2]; v[2] = v[3]; v[3] = t; }
    if (r & 2) { float t = v[0]; v[0] = v[2]; v[2] = t; t = v[1]; v[1] = v[3]; v[3] = t; }
    *(float4*)(out + 16384 + (size_t)(r0 + row) * 256 + 128 + 4 * c) =
        (float4){v[0], v[1], v[2], v[3]};
  }
}

extern "C" void kernel_launch(void* const* d_in, const int* in_sizes, int n_in,
                              void* d_out, int out_size, void* d_ws, size_t ws_size,
                              hipStream_t stream) {
  const float* data = (const float*)d_in[0];    // [32,512,128] fp32
  const float* weight = (const float*)d_in[1];  // [2048,128] fp32
  float* out = (float*)d_out;  // 16384 mem_score + 16*512*256 read_query (fp32)

  u16* wt = (u16*)d_ws;       // [128][2048] bf16 (k-permuted), 512 KiB
  u16* wb = wt + NUMS * DIM;  // [2048][128] bf16, 512 KiB

  cvt_w_k<<<dim3(DIM / 32, NUMS / 32), dim3(32, 8), 0, stream>>>(weight, wb, wt);
  fused_k<<<dim3(ROWS_TOT / MTILE), dim3(512), 0, stream>>>(data, wb, wt, out);
}